// Round 7
// baseline (248.025 us; speedup 1.0000x reference)
//
#include <hip/hip_runtime.h>

typedef __attribute__((ext_vector_type(8))) short bf16x8;
typedef __attribute__((ext_vector_type(4))) float f32x4;
typedef __attribute__((ext_vector_type(8))) unsigned short u16x8;
typedef __attribute__((ext_vector_type(4))) unsigned short u16x4;
typedef __attribute__((ext_vector_type(4))) int i32x4;

static constexpr int Bsz = 2, SQ = 2048, SKV = 4096, Dm = 768, NH = 12, DH = 64;

#define WAITV(N) asm volatile("s_waitcnt vmcnt(" #N ")" ::: "memory")
// s_barrier as inline asm WITH memory clobber: a compile-time memory fence +
// HW barrier. The builtin is NOT an IR-level fence -- LLVM hoisted stage()'s
// global_load_lds above it in round 6, racing with other waves' reads.
#define BARRIER() asm volatile("s_barrier" ::: "memory")

static __device__ __forceinline__ unsigned short f2bf(float f) {
  unsigned int u = __float_as_uint(f);
  u += 0x7fff + ((u >> 16) & 1);          // round-to-nearest-even
  return (unsigned short)(u >> 16);
}

static __device__ __forceinline__ float fexp2(float x) {
#if __has_builtin(__builtin_amdgcn_exp2f)
  return __builtin_amdgcn_exp2f(x);
#else
  float r; asm("v_exp_f32 %0, %1" : "=v"(r) : "v"(x)); return r;
#endif
}

static __device__ __forceinline__ int cvtpk(float lo, float hi) {
  int r; asm("v_cvt_pk_bf16_f32 %0, %1, %2" : "=v"(r) : "v"(lo), "v"(hi));
  return r;
}

// ------- fused fp32 -> bf16 convert of hs+ehs (outputs contiguous) -------
__global__ void cvt2_kernel(const float* __restrict__ a, const float* __restrict__ b,
                            unsigned short* __restrict__ out, int n1, int ntot) {
  int i = blockIdx.x * blockDim.x + threadIdx.x;
  if (i >= ntot) return;
  const float4* p = (i < n1) ? (reinterpret_cast<const float4*>(a) + (size_t)i * 2)
                             : (reinterpret_cast<const float4*>(b) + (size_t)(i - n1) * 2);
  float4 x = p[0], y = p[1];
  u16x8 o;
  o[0] = f2bf(x.x); o[1] = f2bf(x.y); o[2] = f2bf(x.z); o[3] = f2bf(x.w);
  o[4] = f2bf(y.x); o[5] = f2bf(y.y); o[6] = f2bf(y.z); o[7] = f2bf(y.w);
  *(reinterpret_cast<u16x8*>(out) + i) = o;
}

// ------- all four W[k][n] f32 -> WT[n][k] bf16 in one launch ----------
__global__ void wtrans4(const float* __restrict__ Wq, const float* __restrict__ Wk,
                        const float* __restrict__ Wv, const float* __restrict__ Wo,
                        unsigned short* __restrict__ oq, unsigned short* __restrict__ ok,
                        unsigned short* __restrict__ ov, unsigned short* __restrict__ oo) {
  __shared__ float t[32][33];
  const int z = blockIdx.z;
  const float* W = (z == 0) ? Wq : (z == 1) ? Wk : (z == 2) ? Wv : Wo;
  unsigned short* WT = (z == 0) ? oq : (z == 1) ? ok : (z == 2) ? ov : oo;
  int n0 = blockIdx.x * 32, k0 = blockIdx.y * 32;
  int tx = threadIdx.x, ty = threadIdx.y;   // block (32,8)
  #pragma unroll
  for (int i = 0; i < 4; ++i)
    t[ty * 4 + i][tx] = W[(size_t)(k0 + ty * 4 + i) * Dm + n0 + tx];
  __syncthreads();
  #pragma unroll
  for (int i = 0; i < 4; ++i)
    WT[(size_t)(n0 + ty * 4 + i) * Dm + k0 + tx] = f2bf(t[tx][ty * 4 + i]);
}

// ---- V[b*kv][h*64+d] -> VT[b][h][d][pos(kv)] with PV sigma-permutation ----
__global__ void vtrans(const unsigned short* __restrict__ vb, unsigned short* __restrict__ vtp) {
  __shared__ unsigned short t[64][65];
  const int kt = blockIdx.x, h = blockIdx.y, b = blockIdx.z;
  const int tid = threadIdx.x;
  const int kr = tid >> 2, dc = (tid & 3) * 16;
  const unsigned short* src = vb + ((size_t)(b * SKV + kt * 64 + kr)) * Dm + h * DH + dc;
  u16x8 a0 = *(const u16x8*)src, a1 = *(const u16x8*)(src + 8);
  #pragma unroll
  for (int j = 0; j < 8; ++j) { t[kr][dc + j] = a0[j]; t[kr][dc + 8 + j] = a1[j]; }
  __syncthreads();
  const int d = tid >> 2, p0 = (tid & 3) * 16;
  u16x8 o0, o1;
  #pragma unroll
  for (int j = 0; j < 16; ++j) {
    int pos = p0 + j;
    int pos5 = pos & 31;
    int kv5 = ((pos5 >> 3) & 3) * 4 + ((pos5 >> 2) & 1) * 16 + (pos5 & 3);
    int kv = (pos & 32) | kv5;
    unsigned short v = t[kv][d];
    if (j < 8) o0[j] = v; else o1[j - 8] = v;
  }
  unsigned short* dst = vtp + ((size_t)(b * NH + h) * DH + d) * SKV + kt * 64 + p0;
  *(u16x8*)dst = o0;
  *(u16x8*)(dst + 8) = o1;
}

// ---- GEMM body: 3 buffers, depth-2 prefetch, ONE fenced barrier per K-step ----
template <int BM, int BN, bool F32OUT>
static __device__ __forceinline__ void gemm_body(const unsigned short* __restrict__ A,
                                                 const unsigned short* __restrict__ BT,
                                                 const float* __restrict__ bias,
                                                 void* __restrict__ Cout, float scale,
                                                 int row0, int col0,
                                                 unsigned short* As, unsigned short* Bs) {
  const int tid = threadIdx.x;
  const int wave = tid >> 6, lane = tid & 63;
  const int wr = wave >> 1, wc = wave & 1;
  const int lrow = lane & 15, lk8 = (lane >> 4) << 3;
  constexpr int MI = BM / 32, NJ = BN / 32;
  constexpr int AG = BM / 64, BG = BN / 64, LPS = AG + BG;
  f32x4 acc[MI][NJ] = {};

  const unsigned short* ap[AG]; int ae[AG];
  const unsigned short* bp[BG]; int be[BG];
  #pragma unroll
  for (int j = 0; j < AG; ++j) {
    int e = (tid + j * 256) * 8; int r = e >> 5, c = e & 31;
    ap[j] = A + (size_t)(row0 + r) * Dm + c; ae[j] = e;
  }
  #pragma unroll
  for (int j = 0; j < BG; ++j) {
    int e = (tid + j * 256) * 8; int r = e >> 5, c = e & 31;
    bp[j] = BT + (size_t)(col0 + r) * Dm + c; be[j] = e;
  }

  auto stage = [&](int buf) {
    #pragma unroll
    for (int j = 0; j < AG; ++j) {
      __builtin_amdgcn_global_load_lds(
          (const __attribute__((address_space(1))) void*)ap[j],
          (__attribute__((address_space(3))) void*)(As + buf * (BM * 32) + ae[j]), 16, 0, 0);
      ap[j] += 32;
    }
    #pragma unroll
    for (int j = 0; j < BG; ++j) {
      __builtin_amdgcn_global_load_lds(
          (const __attribute__((address_space(1))) void*)bp[j],
          (__attribute__((address_space(3))) void*)(Bs + buf * (BN * 32) + be[j]), 16, 0, 0);
      bp[j] += 32;
    }
  };

  // mode 0: WAITV(LPS) + stage; 1: WAITV(LPS); 2: WAITV(0)
  auto step = [&](int buf, int mode) {
    if (mode < 2) { if constexpr (LPS == 4) { WAITV(4); } else { WAITV(3); } }
    else          { WAITV(0); }
    BARRIER();
    if (mode == 0) stage(buf == 0 ? 2 : buf - 1);   // (buf+2)%3 == buffer read at t-1
    bf16x8 a[MI], b[NJ];
    #pragma unroll
    for (int mi = 0; mi < MI; ++mi)
      a[mi] = *(const bf16x8*)&As[buf * (BM * 32) + (wr * (BM / 2) + mi * 16 + lrow) * 32 + lk8];
    #pragma unroll
    for (int nj = 0; nj < NJ; ++nj)
      b[nj] = *(const bf16x8*)&Bs[buf * (BN * 32) + (wc * (BN / 2) + nj * 16 + lrow) * 32 + lk8];
    #pragma unroll
    for (int mi = 0; mi < MI; ++mi)
      #pragma unroll
      for (int nj = 0; nj < NJ; ++nj)       // swapped: weights as A, acts as B
        acc[mi][nj] = __builtin_amdgcn_mfma_f32_16x16x32_bf16(b[nj], a[mi], acc[mi][nj], 0, 0, 0);
  };

  stage(0); stage(1);
  step(0, 0);                                              // t=0
  for (int base = 1; base <= 19; base += 3) {              // t=1..21
    step(1, 0); step(2, 0); step(0, 0);
  }
  step(1, 1);                                              // t=22
  step(2, 2);                                              // t=23

  // epilogue: lane holds row grow (fixed), 4 consecutive cols per frag
  #pragma unroll
  for (int mi = 0; mi < MI; ++mi) {
    const int grow = row0 + wr * (BM / 2) + mi * 16 + lrow;
    #pragma unroll
    for (int nj = 0; nj < NJ; ++nj) {
      const int gcolb = col0 + wc * (BN / 2) + nj * 16 + ((lane >> 4) << 2);
      const f32x4 bb = *(const f32x4*)&bias[gcolb];
      if constexpr (F32OUT) {
        f32x4 v;
        #pragma unroll
        for (int r = 0; r < 4; ++r) v[r] = (acc[mi][nj][r] + bb[r]) * scale;
        *(f32x4*)((float*)Cout + (size_t)grow * Dm + gcolb) = v;
      } else {
        u16x4 o;
        #pragma unroll
        for (int r = 0; r < 4; ++r) o[r] = f2bf((acc[mi][nj][r] + bb[r]) * scale);
        *(u16x4*)((unsigned short*)Cout + (size_t)grow * Dm + gcolb) = o;
      }
    }
  }
}

// ---- fused Q/K/V projection; Q scaled by log2(e)/8 (log2-domain softmax) ----
__global__ __launch_bounds__(256) void qkv_gemm(const unsigned short* __restrict__ hsb,
                                                const unsigned short* __restrict__ ehsb,
                                                const unsigned short* __restrict__ wqt,
                                                const unsigned short* __restrict__ wkt,
                                                const unsigned short* __restrict__ wvt,
                                                const float* __restrict__ bq,
                                                const float* __restrict__ bk,
                                                const float* __restrict__ bv,
                                                unsigned short* __restrict__ qb,
                                                unsigned short* __restrict__ kb,
                                                unsigned short* __restrict__ vb) {
  __shared__ unsigned short As[3 * 128 * 32];
  __shared__ unsigned short Bs[3 * 128 * 32];
  const int tile = blockIdx.y;
  const unsigned short *A, *BT; const float* bias; unsigned short* out;
  float scale; int row0;
  if (tile < 32)      { A = hsb;  BT = wqt; bias = bq; out = qb; scale = 0.18033688f; row0 = tile * 128; }
  else if (tile < 96) { A = ehsb; BT = wkt; bias = bk; out = kb; scale = 1.0f;        row0 = (tile - 32) * 128; }
  else                { A = ehsb; BT = wvt; bias = bv; out = vb; scale = 1.0f;        row0 = (tile - 96) * 128; }
  gemm_body<128, 128, false>(A, BT, bias, out, scale, row0, blockIdx.x * 128, As, Bs);
}

// ---- O projection: 128x64 tiles -> (12, 32) = 384 blocks ----
__global__ __launch_bounds__(256) void o_gemm(const unsigned short* __restrict__ A,
                                              const unsigned short* __restrict__ BT,
                                              const float* __restrict__ bias,
                                              float* __restrict__ Cout) {
  __shared__ unsigned short As[3 * 128 * 32];
  __shared__ unsigned short Bs[3 * 64 * 32];
  gemm_body<128, 64, true>(A, BT, bias, Cout, 1.0f, blockIdx.y * 128, blockIdx.x * 64, As, Bs);
}

// ------------------------- flash attention ----------------------------
// 2 waves x 32 q-rows: each K/V fragment read from LDS feeds TWO Q-sets
// (halves LDS traffic). Static-max log2 softmax, l via ones-MFMA, swapped
// QK^T / PV. 3 LDS buffers, depth-2 prefetch, ONE fenced barrier per tile.
__global__ __launch_bounds__(128, 2) void attn_kernel(const unsigned short* __restrict__ Q,
                                                      const unsigned short* __restrict__ K,
                                                      const unsigned short* __restrict__ VT,
                                                      unsigned short* __restrict__ Ctx) {
  __shared__ unsigned short Ks[3][64 * 64];
  __shared__ unsigned short Vs[3][64 * 64];
  const int qt = blockIdx.x, h = blockIdx.y, b = blockIdx.z;
  const int tid = threadIdx.x;
  const int wave = tid >> 6, lane = tid & 63;
  const int lrow = lane & 15, lg = lane >> 4, lk8 = lg << 3;
  const size_t qoff = (size_t)b * SQ * Dm + (size_t)h * DH;
  const size_t koff = (size_t)b * SKV * Dm + (size_t)h * DH;
  const size_t voff = (size_t)(b * NH + h) * DH * SKV;

  const int qrow0 = qt * 64 + wave * 32 + lrow;   // q-set 0
  const int qrow1 = qrow0 + 16;                   // q-set 1
  const bf16x8 qa00 = *(const bf16x8*)(Q + qoff + (size_t)qrow0 * Dm + lk8);
  const bf16x8 qa01 = *(const bf16x8*)(Q + qoff + (size_t)qrow0 * Dm + 32 + lk8);
  const bf16x8 qa10 = *(const bf16x8*)(Q + qoff + (size_t)qrow1 * Dm + lk8);
  const bf16x8 qa11 = *(const bf16x8*)(Q + qoff + (size_t)qrow1 * Dm + 32 + lk8);

  bf16x8 ones;
  #pragma unroll
  for (int j = 0; j < 8; ++j) ones[j] = (short)0x3F80;   // bf16 1.0

  const unsigned short* kp[4];
  const unsigned short* vp[4];
  int de[4];
  #pragma unroll
  for (int c = 0; c < 4; ++c) {
    int db = (tid + c * 128) * 16;
    int r = db >> 7, cb = db & 127;
    int sc = (cb ^ ((r & 7) << 4)) >> 1;
    kp[c] = K + koff + (size_t)r * Dm + sc;
    vp[c] = VT + voff + (size_t)r * SKV + sc;
    de[c] = db >> 1;
  }

  auto stage = [&](int buf) {
    #pragma unroll
    for (int c = 0; c < 4; ++c) {
      __builtin_amdgcn_global_load_lds((const __attribute__((address_space(1))) void*)kp[c],
          (__attribute__((address_space(3))) void*)(&Ks[buf][de[c]]), 16, 0, 0);
      __builtin_amdgcn_global_load_lds((const __attribute__((address_space(1))) void*)vp[c],
          (__attribute__((address_space(3))) void*)(&Vs[buf][de[c]]), 16, 0, 0);
      kp[c] += 64 * Dm; vp[c] += 64;
    }
  };

  f32x4 acc0[4] = {}, acc1[4] = {};
  f32x4 accl0 = {}, accl1 = {};
  const int swz = (lrow & 7) << 4;

  // mode 0: WAITV(8)+stage; 1: WAITV(8); 2: WAITV(0)
  auto body = [&](int buf, int mode) {
    if (mode < 2) { WAITV(8); } else { WAITV(0); }
    BARRIER();
    if (mode == 0) stage(buf == 0 ? 2 : buf - 1);   // buffer read at t-1

    // S^T = K * Q^T for both q-sets; kf reads shared
    f32x4 s0[4] = {}, s1[4] = {};
    __builtin_amdgcn_s_setprio(1);
    #pragma unroll
    for (int ks = 0; ks < 2; ++ks) {
      bf16x8 kf[4];
      #pragma unroll
      for (int nj = 0; nj < 4; ++nj) {
        const int cb = (ks * 64 + lg * 16) ^ swz;
        kf[nj] = *(const bf16x8*)((const char*)&Ks[buf][0] + (nj * 16 + lrow) * 128 + cb);
      }
      #pragma unroll
      for (int nj = 0; nj < 4; ++nj) {
        s0[nj] = __builtin_amdgcn_mfma_f32_16x16x32_bf16(kf[nj], ks ? qa01 : qa00, s0[nj], 0, 0, 0);
        s1[nj] = __builtin_amdgcn_mfma_f32_16x16x32_bf16(kf[nj], ks ? qa11 : qa10, s1[nj], 0, 0, 0);
      }
    }
    __builtin_amdgcn_s_setprio(0);

    float e0[4][4], e1[4][4];
    #pragma unroll
    for (int nj = 0; nj < 4; ++nj)
      #pragma unroll
      for (int r = 0; r < 4; ++r) { e0[nj][r] = fexp2(s0[nj][r]); e1[nj][r] = fexp2(s1[nj][r]); }

    #pragma unroll
    for (int ks = 0; ks < 2; ++ks) {
      i32x4 pw0, pw1;
      pw0[0] = cvtpk(e0[2 * ks][0], e0[2 * ks][1]);
      pw0[1] = cvtpk(e0[2 * ks][2], e0[2 * ks][3]);
      pw0[2] = cvtpk(e0[2 * ks + 1][0], e0[2 * ks + 1][1]);
      pw0[3] = cvtpk(e0[2 * ks + 1][2], e0[2 * ks + 1][3]);
      pw1[0] = cvtpk(e1[2 * ks][0], e1[2 * ks][1]);
      pw1[1] = cvtpk(e1[2 * ks][2], e1[2 * ks][3]);
      pw1[2] = cvtpk(e1[2 * ks + 1][0], e1[2 * ks + 1][1]);
      pw1[3] = cvtpk(e1[2 * ks + 1][2], e1[2 * ks + 1][3]);
      bf16x8 pa0 = __builtin_bit_cast(bf16x8, pw0);
      bf16x8 pa1 = __builtin_bit_cast(bf16x8, pw1);
      __builtin_amdgcn_s_setprio(1);
      #pragma unroll
      for (int dj = 0; dj < 4; ++dj) {
        const int cb = (ks * 64 + lg * 16) ^ swz;
        bf16x8 vf = *(const bf16x8*)((const char*)&Vs[buf][0] + (dj * 16 + lrow) * 128 + cb);
        acc0[dj] = __builtin_amdgcn_mfma_f32_16x16x32_bf16(vf, pa0, acc0[dj], 0, 0, 0);
        acc1[dj] = __builtin_amdgcn_mfma_f32_16x16x32_bf16(vf, pa1, acc1[dj], 0, 0, 0);
      }
      accl0 = __builtin_amdgcn_mfma_f32_16x16x32_bf16(ones, pa0, accl0, 0, 0, 0);
      accl1 = __builtin_amdgcn_mfma_f32_16x16x32_bf16(ones, pa1, accl1, 0, 0, 0);
      __builtin_amdgcn_s_setprio(0);
    }
  };

  stage(0); stage(1);
  body(0, 0);                                              // t=0
  for (int base = 1; base <= 58; base += 3) {              // t=1..60
    body(1, 0); body(2, 0); body(0, 0);
  }
  body(1, 0);                                              // t=61 (stages t=63)
  body(2, 1);                                              // t=62
  body(0, 2);                                              // t=63

  const float li0 = 1.0f / accl0[0];
  const float li1 = 1.0f / accl1[0];
  #pragma unroll
  for (int dj = 0; dj < 4; ++dj) {
    u16x4 o0, o1;
    #pragma unroll
    for (int r = 0; r < 4; ++r) { o0[r] = f2bf(acc0[dj][r] * li0); o1[r] = f2bf(acc1[dj][r] * li1); }
    *(u16x4*)(Ctx + qoff + (size_t)qrow0 * Dm + dj * 16 + (lg << 2)) = o0;
    *(u16x4*)(Ctx + qoff + (size_t)qrow1 * Dm + dj * 16 + (lg << 2)) = o1;
  }
}

extern "C" void kernel_launch(void* const* d_in, const int* in_sizes, int n_in,
                              void* d_out, int out_size, void* d_ws, size_t ws_size,
                              hipStream_t stream) {
  const float* hs  = (const float*)d_in[0];
  const float* ehs = (const float*)d_in[1];
  const float* Wq  = (const float*)d_in[2];
  const float* bq  = (const float*)d_in[3];
  const float* Wk  = (const float*)d_in[4];
  const float* bk  = (const float*)d_in[5];
  const float* Wv  = (const float*)d_in[6];
  const float* bv  = (const float*)d_in[7];
  const float* Wo  = (const float*)d_in[8];
  const float* bo  = (const float*)d_in[9];
  float* out = (float*)d_out;

  unsigned short* hsb  = (unsigned short*)d_ws;
  unsigned short* ehsb = hsb  + (size_t)Bsz * SQ * Dm;
  unsigned short* wqt  = ehsb + (size_t)Bsz * SKV * Dm;
  unsigned short* wkt  = wqt + (size_t)Dm * Dm;
  unsigned short* wvt  = wkt + (size_t)Dm * Dm;
  unsigned short* wot  = wvt + (size_t)Dm * Dm;
  unsigned short* qb   = wot + (size_t)Dm * Dm;
  unsigned short* kb   = qb  + (size_t)Bsz * SQ * Dm;
  unsigned short* vb   = kb  + (size_t)Bsz * SKV * Dm;
  unsigned short* ctxb = vb  + (size_t)Bsz * SKV * Dm;
  unsigned short* vtp  = ehsb;   // ehsb dead after qkv_gemm

  const int nHS = Bsz * SQ * Dm, nEHS = Bsz * SKV * Dm;
  const int n1 = nHS / 8, ntot = (nHS + nEHS) / 8;
  cvt2_kernel<<<(ntot + 255) / 256, 256, 0, stream>>>(hs, ehs, hsb, n1, ntot);

  wtrans4<<<dim3(24, 24, 4), dim3(32, 8), 0, stream>>>(Wq, Wk, Wv, Wo, wqt, wkt, wvt, wot);

  qkv_gemm<<<dim3(6, 160), 256, 0, stream>>>(hsb, ehsb, wqt, wkt, wvt, bq, bk, bv, qb, kb, vb);

  vtrans<<<dim3(SKV / 64, NH, Bsz), 256, 0, stream>>>(vb, vtp);

  attn_kernel<<<dim3(SQ / 64, NH, Bsz), 128, 0, stream>>>(qb, kb, vtp, ctxb);

  o_gemm<<<dim3(12, 32), 256, 0, stream>>>(ctxb, wot, bo, out);
}